// Round 9
// baseline (152.479 us; speedup 1.0000x reference)
//
#include <hip/hip_runtime.h>

// BlocksparseFixedSelfAttention: B=4, T=2048, EMB=512, KBLK=64.
// R9 = R8 with heads restructured: 512 threads, grid (32,4,2). 8 waves split
// Phase A (4 waves S1 strips, 4 waves S2 strips; shared K/Q/Qs panels), S
// computed 2x instead of 4x; Phase B covers 256 e-cols in two 128-col passes.
// prep / wc / kqv identical to R8.
// ws (MB): KQV bf16 8192x1536 24 @0 | xb 8 @24 | wcat bf16 2048x512 @32 |
//          vu2sel bf16 128x512 @34 | wvtb @35 | wub @36 | biascat @37

typedef unsigned short u16;
typedef __attribute__((ext_vector_type(8))) short short8;
typedef __attribute__((ext_vector_type(4))) float f32x4;

constexpr int TDIM  = 2048;
constexpr int EMB_D = 512;
constexpr int BB    = 4;
constexpr int NBLK  = 32;    // T / 64
constexpr int LDK   = 1536;  // KQV row stride (u16): [K|Q|VU1]

__device__ __forceinline__ u16 f2b(float f) {
    unsigned u = __float_as_uint(f);
    unsigned r = (u + 0x7FFFu + ((u >> 16) & 1u)) >> 16;
    return (u16)r;
}

// ---------------------------------------------------------------------------
// prep (R8): casts + Wv transpose + bias.
// ---------------------------------------------------------------------------
__global__ __launch_bounds__(256) void prep_k(
    const float* __restrict__ x, const float* __restrict__ Wk, const float* __restrict__ Wq,
    const float* __restrict__ Wv, const float* __restrict__ Wu,
    const float* __restrict__ bk, const float* __restrict__ bq, const float* __restrict__ bv,
    u16* __restrict__ xb, u16* __restrict__ wcat, u16* __restrict__ wvtb,
    u16* __restrict__ wub, float* __restrict__ biascat)
{
    const int bid = blockIdx.x, tid = threadIdx.x;
    if (bid < 5120) {
        const float* src; u16* dst; int base;
        if (bid < 4096)      { src = x;  dst = xb;            base = bid * 1024; }
        else if (bid < 4352) { src = Wk; dst = wcat;          base = (bid - 4096) * 1024; }
        else if (bid < 4608) { src = Wq; dst = wcat + 262144; base = (bid - 4352) * 1024; }
        else                 { src = Wu; dst = wub;           base = (bid - 4608) * 1024; }
        const int idx = base + tid * 4;
        float4 v = *(const float4*)(src + idx);
        ushort4 o = { f2b(v.x), f2b(v.y), f2b(v.z), f2b(v.w) };
        *(ushort4*)(dst + idx) = o;
    } else if (bid < 5184) {
        __shared__ float T[64][65];
        const int t = bid - 5120;
        const int j0 = (t >> 3) * 64, k0 = (t & 7) * 64;
        const int rr = tid >> 4, c4 = (tid & 15) * 4;
        #pragma unroll
        for (int it = 0; it < 4; ++it) {
            const int j = rr + it * 16;
            float4 v = *(const float4*)(Wv + (size_t)(j0 + j) * 512 + k0 + c4);
            T[c4+0][j] = v.x; T[c4+1][j] = v.y; T[c4+2][j] = v.z; T[c4+3][j] = v.w;
        }
        __syncthreads();
        #pragma unroll
        for (int it = 0; it < 4; ++it) {
            const int k = rr + it * 16;
            ushort4 o = { f2b(T[k][c4+0]), f2b(T[k][c4+1]), f2b(T[k][c4+2]), f2b(T[k][c4+3]) };
            *(ushort4*)(wvtb + (size_t)(k0 + k) * 512 + j0 + c4) = o;
        }
    } else if (bid < 5200) {
        const int o = (bid - 5184) * 64 + (tid >> 2);
        const int p = tid & 3;
        const int n = o & 511, half = o >> 9;
        const float* wr = Wu + (size_t)n * 1024 + half * 512 + p * 128;
        const float* br = bv + p * 128;
        float s = 0.f;
        #pragma unroll
        for (int j = 0; j < 128; j += 4) {
            float4 a = *(const float4*)(wr + j);
            float4 b = *(const float4*)(br + j);
            s += a.x*b.x + a.y*b.y + a.z*b.z + a.w*b.w;
        }
        s += __shfl_xor(s, 1);
        s += __shfl_xor(s, 2);
        if (p == 0) biascat[1024 + o] = s;
    } else {
        const int idx = tid * 4;
        float4 v = (idx < 512) ? *(const float4*)(bk + idx)
                               : *(const float4*)(bq + idx - 512);
        *(float4*)(biascat + idx) = v;
    }
}

// ---------------------------------------------------------------------------
// wc_gemm (R8): Wc = Wu.Wv -> wcat rows 1024+. bf16 MFMA 128x128, BK=32.
// ---------------------------------------------------------------------------
__global__ __launch_bounds__(256) void wc_gemm_k(
    const u16* __restrict__ wub, const u16* __restrict__ wvtb, u16* __restrict__ wcat)
{
    __shared__ u16 As[128 * 32];
    __shared__ u16 Bs[128 * 32];
    const int bm = blockIdx.x * 128;
    const int bn = blockIdx.y * 128;
    const int tid  = threadIdx.x;
    const int wid  = tid >> 6;
    const int lane = tid & 63;
    const int l15  = lane & 15;
    const int quad = lane >> 4;
    const int wm = (wid & 1) * 64;
    const int wn = (wid >> 1) * 64;
    f32x4 acc[4][4] = {};
    const int srow  = tid >> 2;
    const int skoff = (tid & 3) * 8;
    const int m0 = bm + srow, m1 = bm + 64 + srow;
    const u16* Ag0 = wub + (size_t)(m0 & 511) * 1024 + (m0 >> 9) * 512 + skoff;
    const u16* Ag1 = wub + (size_t)(m1 & 511) * 1024 + (m1 >> 9) * 512 + skoff;
    const u16* Bg  = wvtb + (size_t)(bn + srow) * 512 + skoff;
    char* AsBase = (char*)As + wid * 1024;
    char* BsBase = (char*)Bs + wid * 1024;

    for (int k0 = 0; k0 < 512; k0 += 32) {
        __syncthreads();
        __builtin_amdgcn_global_load_lds(
            (const __attribute__((address_space(1))) void*)(Ag0 + k0),
            (__attribute__((address_space(3))) void*)AsBase, 16, 0, 0);
        __builtin_amdgcn_global_load_lds(
            (const __attribute__((address_space(1))) void*)(Ag1 + k0),
            (__attribute__((address_space(3))) void*)(AsBase + 4096), 16, 0, 0);
        __builtin_amdgcn_global_load_lds(
            (const __attribute__((address_space(1))) void*)(Bg + k0),
            (__attribute__((address_space(3))) void*)BsBase, 16, 0, 0);
        __builtin_amdgcn_global_load_lds(
            (const __attribute__((address_space(1))) void*)(Bg + (size_t)64 * 512 + k0),
            (__attribute__((address_space(3))) void*)(BsBase + 4096), 16, 0, 0);
        __syncthreads();

        short8 a[4], b[4];
        #pragma unroll
        for (int i = 0; i < 4; ++i)
            a[i] = *(const short8*)((const short*)As + (wm + 16*i + l15) * 32 + quad * 8);
        #pragma unroll
        for (int j = 0; j < 4; ++j)
            b[j] = *(const short8*)((const short*)Bs + (wn + 16*j + l15) * 32 + quad * 8);
        #pragma unroll
        for (int i = 0; i < 4; ++i)
            #pragma unroll
            for (int j = 0; j < 4; ++j)
                acc[i][j] = __builtin_amdgcn_mfma_f32_16x16x32_bf16(a[i], b[j], acc[i][j], 0, 0, 0);
    }
    #pragma unroll
    for (int i = 0; i < 4; ++i)
        #pragma unroll
        for (int j = 0; j < 4; ++j) {
            const int col = bn + wn + 16*j + l15;
            #pragma unroll
            for (int r = 0; r < 4; ++r) {
                const int row = bm + wm + 16*i + quad*4 + r;
                wcat[(size_t)(1024 + row) * 512 + col] = f2b(acc[i][j][r]);
            }
        }
}

// ---------------------------------------------------------------------------
// kqv (R8): grid (65,12). x<64: KQV=[K|Q|VU1]; x==64,y<4: vu2sel.
// ---------------------------------------------------------------------------
__global__ __launch_bounds__(256) void kqv_k(
    const u16* __restrict__ xb, const u16* __restrict__ wcat,
    const float* __restrict__ biascat, u16* __restrict__ KQV, u16* __restrict__ vu2sel)
{
    __shared__ u16 As[128 * 32];
    __shared__ u16 Bs[128 * 32];
    const int tid  = threadIdx.x;
    const int wid  = tid >> 6;
    const int lane = tid & 63;
    const int l15  = lane & 15;
    const int quad = lane >> 4;
    const int wm = (wid & 1) * 64;
    const int wn = (wid >> 1) * 64;
    const int srow  = tid >> 2;
    const int skoff = (tid & 3) * 8;
    char* AsBase = (char*)As + wid * 1024;
    char* BsBase = (char*)Bs + wid * 1024;
    f32x4 acc[4][4] = {};

    const bool sel = (blockIdx.x == 64);
    if (sel && blockIdx.y >= 4) return;

    const u16 *Ag0, *Ag1, *Bg;
    const int bn = blockIdx.y * 128;
    if (!sel) {
        const int bm = blockIdx.x * 128;
        Ag0 = xb + (size_t)(bm + srow) * EMB_D + skoff;
        Ag1 = Ag0 + (size_t)64 * EMB_D;
        Bg  = wcat + (size_t)(bn + srow) * EMB_D + skoff;
    } else {
        const int r0 = srow, r1 = srow + 64;
        const int g0 = (r0 >> 5) * TDIM + (r0 & 31) * 64;
        const int g1 = (r1 >> 5) * TDIM + (r1 & 31) * 64;
        Ag0 = xb + (size_t)g0 * EMB_D + skoff;
        Ag1 = xb + (size_t)g1 * EMB_D + skoff;
        Bg  = wcat + (size_t)(1536 + bn + srow) * EMB_D + skoff;
    }

    for (int k0 = 0; k0 < EMB_D; k0 += 32) {
        __syncthreads();
        __builtin_amdgcn_global_load_lds(
            (const __attribute__((address_space(1))) void*)(Ag0 + k0),
            (__attribute__((address_space(3))) void*)AsBase, 16, 0, 0);
        __builtin_amdgcn_global_load_lds(
            (const __attribute__((address_space(1))) void*)(Ag1 + k0),
            (__attribute__((address_space(3))) void*)(AsBase + 4096), 16, 0, 0);
        __builtin_amdgcn_global_load_lds(
            (const __attribute__((address_space(1))) void*)(Bg + k0),
            (__attribute__((address_space(3))) void*)BsBase, 16, 0, 0);
        __builtin_amdgcn_global_load_lds(
            (const __attribute__((address_space(1))) void*)(Bg + (size_t)64 * EMB_D + k0),
            (__attribute__((address_space(3))) void*)(BsBase + 4096), 16, 0, 0);
        __syncthreads();

        short8 a[4], b[4];
        #pragma unroll
        for (int i = 0; i < 4; ++i)
            a[i] = *(const short8*)((const short*)As + (wm + 16*i + l15) * 32 + quad * 8);
        #pragma unroll
        for (int j = 0; j < 4; ++j)
            b[j] = *(const short8*)((const short*)Bs + (wn + 16*j + l15) * 32 + quad * 8);
        #pragma unroll
        for (int i = 0; i < 4; ++i)
            #pragma unroll
            for (int j = 0; j < 4; ++j)
                acc[i][j] = __builtin_amdgcn_mfma_f32_16x16x32_bf16(a[i], b[j], acc[i][j], 0, 0, 0);
    }

    if (!sel) {
        const int bm = blockIdx.x * 128;
        #pragma unroll
        for (int i = 0; i < 4; ++i)
            #pragma unroll
            for (int j = 0; j < 4; ++j) {
                const int col = bn + wn + 16*j + l15;
                const float bvv = biascat[col];
                #pragma unroll
                for (int r = 0; r < 4; ++r) {
                    const int row = bm + wm + 16*i + quad*4 + r;
                    KQV[(size_t)row * LDK + col] = f2b(acc[i][j][r] + bvv);
                }
            }
    } else {
        #pragma unroll
        for (int i = 0; i < 4; ++i)
            #pragma unroll
            for (int j = 0; j < 4; ++j) {
                const int col = bn + wn + 16*j + l15;
                const float bvv = biascat[1536 + col];
                #pragma unroll
                for (int r = 0; r < 4; ++r) {
                    const int row = wm + 16*i + quad*4 + r;
                    vu2sel[(size_t)row * 512 + col] = f2b(acc[i][j][r] + bvv);
                }
            }
    }
}

// ---------------------------------------------------------------------------
// heads: grid (32 blk, 4 b, 2 z), 512 threads (8 waves).
//  Phase A (BK=64, 8 iters): waves 0-3 compute 16-row strips of S1 (64x64),
//  waves 4-7 strips of S2 (64x32); K/Q/Qs panels shared. masks c<=r / m<=blk.
//  Phase B: two 128-col passes over e-chunk z*256: out = [S1|S2]@VT + bu.
//  Wave w: rows 16*(w&3), col-half (w>>2).
// ---------------------------------------------------------------------------
__global__ __launch_bounds__(512) void heads_k(
    const u16* __restrict__ KQV, const u16* __restrict__ vu2sel,
    const float* __restrict__ bu, float* __restrict__ out)
{
    __shared__ u16 smA[64 * 104];     // [row][0:64 S1 | 64:96 S2]
    __shared__ u16 smVT[128 * 104];   // [e][0:64 VU1^T | 64:96 VU2sel^T] (per pass)
    __shared__ u16 pK[2][64 * 32];    // BK=64 = 2 x 32 panels
    __shared__ u16 pQ[2][64 * 32];
    __shared__ u16 pQs[2][32 * 32];

    const int blk = blockIdx.x, b = blockIdx.y, z = blockIdx.z;
    const int tid = threadIdx.x;
    const int wid = tid >> 6, lane = tid & 63;
    const int l15 = lane & 15, quad = lane >> 4;
    const size_t row0 = (size_t)b * TDIM + (size_t)blk * 64;
    const size_t brow = (size_t)b * TDIM;
    const int ebase = z * 256;

    // ---- stage VT pass 0 (independent of Phase A; overlaps its latency) ----
    {
        const int ec0 = ebase;
        #pragma unroll
        for (int it = 0; it < 2; ++it) {
            const int id = tid + 512 * it;
            const int c  = id & 63;
            const int eo = (id >> 6) * 8;
            short8 v = *(const short8*)(KQV + (row0 + c) * (size_t)LDK + 1024 + ec0 + eo);
            #pragma unroll
            for (int i = 0; i < 8; ++i) smVT[(eo + i) * 104 + c] = (u16)v[i];
        }
        {
            const int m  = tid & 31;
            const int eo = (tid >> 5) * 8;
            short8 v = *(const short8*)(vu2sel + ((size_t)(b * 32 + m)) * 512 + ec0 + eo);
            #pragma unroll
            for (int i = 0; i < 8; ++i) smVT[(eo + i) * 104 + 64 + m] = (u16)v[i];
        }
    }

    // ---- Phase A (BK=64, 8 iters; 8 waves) ----
    // staging: half h = tid>>8 stages k-sub-panel h (rows (tid&255)>>2, k (tid&3)*8)
    f32x4 s[4] = {};
    const int h      = tid >> 8;
    const int hrow   = (tid & 255) >> 2;
    const int skoff  = (tid & 3) * 8;
    const u16* Kg  = KQV + (row0 + hrow) * (size_t)LDK + h * 32 + skoff;
    const u16* Qg  = KQV + (row0 + hrow) * (size_t)LDK + 512 + h * 32 + skoff;
    const int qsrow = hrow & 31;
    const int qsp   = (tid & 255) >> 7;
    const u16* Qsg = KQV + (brow + (size_t)64 * qsrow) * (size_t)LDK + 512 + qsp * 32 + skoff;
    char* dK  = (char*)pK  + h * 4096 + (wid & 3) * 1024;
    char* dQ  = (char*)pQ  + h * 4096 + (wid & 3) * 1024;
    char* dQs = (char*)pQs + (wid & 3) * 1024;   // waves 0-3 only (covers both panels)

    const bool isS1 = (wid < 4);
    const int strip = wid & 3;                    // 16-row strip index
    const int arow_off = (strip * 16 + l15) * 32 + quad * 8;

    for (int k0 = 0; k0 < 512; k0 += 64) {
        __syncthreads();
        __builtin_amdgcn_global_load_lds(
            (const __attribute__((address_space(1))) void*)(Kg + k0),
            (__attribute__((address_space(3))) void*)dK, 16, 0, 0);
        __builtin_amdgcn_global_load_lds(
            (const __attribute__((address_space(1))) void*)(Qg + k0),
            (__attribute__((address_space(3))) void*)dQ, 16, 0, 0);
        if (tid < 256)
            __builtin_amdgcn_global_load_lds(
                (const __attribute__((address_space(1))) void*)(Qsg + k0),
                (__attribute__((address_space(3))) void*)dQs, 16, 0, 0);
        __syncthreads();

        short8 a0 = *(const short8*)(pK[0] + arow_off);
        short8 a1 = *(const short8*)(pK[1] + arow_off);
        if (isS1) {
            #pragma unroll
            for (int j = 0; j < 4; ++j) {
                short8 b0 = *(const short8*)(pQ[0] + (16 * j + l15) * 32 + quad * 8);
                short8 b1 = *(const short8*)(pQ[1] + (16 * j + l15) * 32 + quad * 8);
                s[j] = __builtin_amdgcn_mfma_f32_16x16x32_bf16(a0, b0, s[j], 0, 0, 0);
                s[j] = __builtin_amdgcn_mfma_f32_16x16x32_bf16(a1, b1, s[j], 0, 0, 0);
            }
        } else {
            #pragma unroll
            for (int j = 0; j < 2; ++j) {
                short8 b0 = *(const short8*)(pQs[0] + (16 * j + l15) * 32 + quad * 8);
                short8 b1 = *(const short8*)(pQs[1] + (16 * j + l15) * 32 + quad * 8);
                s[j] = __builtin_amdgcn_mfma_f32_16x16x32_bf16(a0, b0, s[j], 0, 0, 0);
                s[j] = __builtin_amdgcn_mfma_f32_16x16x32_bf16(a1, b1, s[j], 0, 0, 0);
            }
        }
    }

    // mask + store S strips to smA (bf16)
    {
        const int rbase = strip * 16 + quad * 4;
        if (isS1) {
            #pragma unroll
            for (int j = 0; j < 4; ++j)
                #pragma unroll
                for (int r = 0; r < 4; ++r) {
                    const int rr = rbase + r;
                    const int cc = 16 * j + l15;
                    smA[rr * 104 + cc] = f2b((cc <= rr) ? s[j][r] : 0.0f);
                }
        } else {
            #pragma unroll
            for (int j = 0; j < 2; ++j)
                #pragma unroll
                for (int r = 0; r < 4; ++r) {
                    const int m  = 16 * j + l15;
                    const int rr = rbase + r;
                    smA[rr * 104 + 64 + m] = f2b((m <= blk) ? s[j][r] : 0.0f);
                }
        }
    }
    __syncthreads();   // smA + smVT(pass 0) ready

    // ---- Phase B: two passes of 128 cols. Wave w: rows 16*(w&3), col-half w>>2.
    const int rbase = (wid & 3) * 16;
    const int chalf = (wid >> 2) * 64;
    const u16* arow = smA + (rbase + l15) * 104;
    for (int p = 0; p < 2; ++p) {
        if (p == 1) {
            __syncthreads();   // pass-0 PV reads done
            const int ec0 = ebase + 128;
            #pragma unroll
            for (int it = 0; it < 2; ++it) {
                const int id = tid + 512 * it;
                const int c  = id & 63;
                const int eo = (id >> 6) * 8;
                short8 v = *(const short8*)(KQV + (row0 + c) * (size_t)LDK + 1024 + ec0 + eo);
                #pragma unroll
                for (int i = 0; i < 8; ++i) smVT[(eo + i) * 104 + c] = (u16)v[i];
            }
            {
                const int m  = tid & 31;
                const int eo = (tid >> 5) * 8;
                short8 v = *(const short8*)(vu2sel + ((size_t)(b * 32 + m)) * 512 + ec0 + eo);
                #pragma unroll
                for (int i = 0; i < 8; ++i) smVT[(eo + i) * 104 + 64 + m] = (u16)v[i];
            }
            __syncthreads();
        }
        f32x4 o[4] = {};
        #pragma unroll
        for (int ks = 0; ks < 3; ++ks) {
            short8 as = *(const short8*)(arow + 32 * ks + quad * 8);
            #pragma unroll
            for (int nt = 0; nt < 4; ++nt) {
                short8 bs = *(const short8*)(smVT + (chalf + 16 * nt + l15) * 104 + 32 * ks + quad * 8);
                o[nt] = __builtin_amdgcn_mfma_f32_16x16x32_bf16(as, bs, o[nt], 0, 0, 0);
            }
        }
        #pragma unroll
        for (int nt = 0; nt < 4; ++nt) {
            const int col = ebase + p * 128 + chalf + 16 * nt + l15;
            const float bvv = bu[col];
            #pragma unroll
            for (int r = 0; r < 4; ++r)
                out[(row0 + rbase + quad * 4 + r) * (size_t)EMB_D + col] = o[nt][r] + bvv;
        }
    }
}

extern "C" void kernel_launch(void* const* d_in, const int* in_sizes, int n_in,
                              void* d_out, int out_size, void* d_ws, size_t ws_size,
                              hipStream_t stream)
{
    const float* x  = (const float*)d_in[0];
    const float* Wk = (const float*)d_in[1];
    const float* bk = (const float*)d_in[2];
    const float* Wq = (const float*)d_in[3];
    const float* bq = (const float*)d_in[4];
    const float* Wv = (const float*)d_in[5];
    const float* bv = (const float*)d_in[6];
    const float* Wu = (const float*)d_in[7];
    const float* bu = (const float*)d_in[8];
    float* out = (float*)d_out;

    char* w = (char*)d_ws;
    u16*   KQV     = (u16*)  (w + ((size_t)0  << 20));
    u16*   xb      = (u16*)  (w + ((size_t)24 << 20));
    u16*   wcat    = (u16*)  (w + ((size_t)32 << 20));
    u16*   vu2sel  = (u16*)  (w + ((size_t)34 << 20));
    u16*   wvtb    = (u16*)  (w + ((size_t)35 << 20));
    u16*   wub     = (u16*)  (w + ((size_t)36 << 20));
    float* biascat = (float*)(w + ((size_t)37 << 20));

    dim3 blk(256);
    hipLaunchKernelGGL(prep_k, dim3(5201), blk, 0, stream,
                       x, Wk, Wq, Wv, Wu, bk, bq, bv, xb, wcat, wvtb, wub, biascat);
    hipLaunchKernelGGL(wc_gemm_k, dim3(8, 4), blk, 0, stream, wub, wvtb, wcat);
    hipLaunchKernelGGL(kqv_k, dim3(65, 12), blk, 0, stream,
                       xb, wcat, biascat, KQV, vu2sel);
    hipLaunchKernelGGL(heads_k, dim3(NBLK, BB, 2), dim3(512), 0, stream,
                       KQV, vu2sel, bu, out);
}

// Round 10
// 148.430 us; speedup vs baseline: 1.0273x; 1.0273x over previous
//
#include <hip/hip_runtime.h>

// BlocksparseFixedSelfAttention: B=4, T=2048, EMB=512, KBLK=64.
// R10 = R8 with kqv BK=64 (two split 32-panels, 32 MFMA per barrier pair,
// halved barrier drains). prep / wc / heads identical to R8.
// ws (MB): KQV bf16 8192x1536 24 @0 | xb 8 @24 | wcat bf16 2048x512 @32 |
//          vu2sel bf16 128x512 @34 | wvtb @35 | wub @36 | biascat @37

typedef unsigned short u16;
typedef __attribute__((ext_vector_type(8))) short short8;
typedef __attribute__((ext_vector_type(4))) float f32x4;

constexpr int TDIM  = 2048;
constexpr int EMB_D = 512;
constexpr int BB    = 4;
constexpr int NBLK  = 32;    // T / 64
constexpr int LDK   = 1536;  // KQV row stride (u16): [K|Q|VU1]

__device__ __forceinline__ u16 f2b(float f) {
    unsigned u = __float_as_uint(f);
    unsigned r = (u + 0x7FFFu + ((u >> 16) & 1u)) >> 16;
    return (u16)r;
}

// ---------------------------------------------------------------------------
// prep (R8): casts + Wv transpose + bias.
// ---------------------------------------------------------------------------
__global__ __launch_bounds__(256) void prep_k(
    const float* __restrict__ x, const float* __restrict__ Wk, const float* __restrict__ Wq,
    const float* __restrict__ Wv, const float* __restrict__ Wu,
    const float* __restrict__ bk, const float* __restrict__ bq, const float* __restrict__ bv,
    u16* __restrict__ xb, u16* __restrict__ wcat, u16* __restrict__ wvtb,
    u16* __restrict__ wub, float* __restrict__ biascat)
{
    const int bid = blockIdx.x, tid = threadIdx.x;
    if (bid < 5120) {
        const float* src; u16* dst; int base;
        if (bid < 4096)      { src = x;  dst = xb;            base = bid * 1024; }
        else if (bid < 4352) { src = Wk; dst = wcat;          base = (bid - 4096) * 1024; }
        else if (bid < 4608) { src = Wq; dst = wcat + 262144; base = (bid - 4352) * 1024; }
        else                 { src = Wu; dst = wub;           base = (bid - 4608) * 1024; }
        const int idx = base + tid * 4;
        float4 v = *(const float4*)(src + idx);
        ushort4 o = { f2b(v.x), f2b(v.y), f2b(v.z), f2b(v.w) };
        *(ushort4*)(dst + idx) = o;
    } else if (bid < 5184) {
        __shared__ float T[64][65];
        const int t = bid - 5120;
        const int j0 = (t >> 3) * 64, k0 = (t & 7) * 64;
        const int rr = tid >> 4, c4 = (tid & 15) * 4;
        #pragma unroll
        for (int it = 0; it < 4; ++it) {
            const int j = rr + it * 16;
            float4 v = *(const float4*)(Wv + (size_t)(j0 + j) * 512 + k0 + c4);
            T[c4+0][j] = v.x; T[c4+1][j] = v.y; T[c4+2][j] = v.z; T[c4+3][j] = v.w;
        }
        __syncthreads();
        #pragma unroll
        for (int it = 0; it < 4; ++it) {
            const int k = rr + it * 16;
            ushort4 o = { f2b(T[k][c4+0]), f2b(T[k][c4+1]), f2b(T[k][c4+2]), f2b(T[k][c4+3]) };
            *(ushort4*)(wvtb + (size_t)(k0 + k) * 512 + j0 + c4) = o;
        }
    } else if (bid < 5200) {
        const int o = (bid - 5184) * 64 + (tid >> 2);
        const int p = tid & 3;
        const int n = o & 511, half = o >> 9;
        const float* wr = Wu + (size_t)n * 1024 + half * 512 + p * 128;
        const float* br = bv + p * 128;
        float s = 0.f;
        #pragma unroll
        for (int j = 0; j < 128; j += 4) {
            float4 a = *(const float4*)(wr + j);
            float4 b = *(const float4*)(br + j);
            s += a.x*b.x + a.y*b.y + a.z*b.z + a.w*b.w;
        }
        s += __shfl_xor(s, 1);
        s += __shfl_xor(s, 2);
        if (p == 0) biascat[1024 + o] = s;
    } else {
        const int idx = tid * 4;
        float4 v = (idx < 512) ? *(const float4*)(bk + idx)
                               : *(const float4*)(bq + idx - 512);
        *(float4*)(biascat + idx) = v;
    }
}

// ---------------------------------------------------------------------------
// wc_gemm (R8): Wc = Wu.Wv -> wcat rows 1024+. bf16 MFMA 128x128, BK=32.
// ---------------------------------------------------------------------------
__global__ __launch_bounds__(256) void wc_gemm_k(
    const u16* __restrict__ wub, const u16* __restrict__ wvtb, u16* __restrict__ wcat)
{
    __shared__ u16 As[128 * 32];
    __shared__ u16 Bs[128 * 32];
    const int bm = blockIdx.x * 128;
    const int bn = blockIdx.y * 128;
    const int tid  = threadIdx.x;
    const int wid  = tid >> 6;
    const int lane = tid & 63;
    const int l15  = lane & 15;
    const int quad = lane >> 4;
    const int wm = (wid & 1) * 64;
    const int wn = (wid >> 1) * 64;
    f32x4 acc[4][4] = {};
    const int srow  = tid >> 2;
    const int skoff = (tid & 3) * 8;
    const int m0 = bm + srow, m1 = bm + 64 + srow;
    const u16* Ag0 = wub + (size_t)(m0 & 511) * 1024 + (m0 >> 9) * 512 + skoff;
    const u16* Ag1 = wub + (size_t)(m1 & 511) * 1024 + (m1 >> 9) * 512 + skoff;
    const u16* Bg  = wvtb + (size_t)(bn + srow) * 512 + skoff;
    char* AsBase = (char*)As + wid * 1024;
    char* BsBase = (char*)Bs + wid * 1024;

    for (int k0 = 0; k0 < 512; k0 += 32) {
        __syncthreads();
        __builtin_amdgcn_global_load_lds(
            (const __attribute__((address_space(1))) void*)(Ag0 + k0),
            (__attribute__((address_space(3))) void*)AsBase, 16, 0, 0);
        __builtin_amdgcn_global_load_lds(
            (const __attribute__((address_space(1))) void*)(Ag1 + k0),
            (__attribute__((address_space(3))) void*)(AsBase + 4096), 16, 0, 0);
        __builtin_amdgcn_global_load_lds(
            (const __attribute__((address_space(1))) void*)(Bg + k0),
            (__attribute__((address_space(3))) void*)BsBase, 16, 0, 0);
        __builtin_amdgcn_global_load_lds(
            (const __attribute__((address_space(1))) void*)(Bg + (size_t)64 * 512 + k0),
            (__attribute__((address_space(3))) void*)(BsBase + 4096), 16, 0, 0);
        __syncthreads();

        short8 a[4], b[4];
        #pragma unroll
        for (int i = 0; i < 4; ++i)
            a[i] = *(const short8*)((const short*)As + (wm + 16*i + l15) * 32 + quad * 8);
        #pragma unroll
        for (int j = 0; j < 4; ++j)
            b[j] = *(const short8*)((const short*)Bs + (wn + 16*j + l15) * 32 + quad * 8);
        #pragma unroll
        for (int i = 0; i < 4; ++i)
            #pragma unroll
            for (int j = 0; j < 4; ++j)
                acc[i][j] = __builtin_amdgcn_mfma_f32_16x16x32_bf16(a[i], b[j], acc[i][j], 0, 0, 0);
    }
    #pragma unroll
    for (int i = 0; i < 4; ++i)
        #pragma unroll
        for (int j = 0; j < 4; ++j) {
            const int col = bn + wn + 16*j + l15;
            #pragma unroll
            for (int r = 0; r < 4; ++r) {
                const int row = bm + wm + 16*i + quad*4 + r;
                wcat[(size_t)(1024 + row) * 512 + col] = f2b(acc[i][j][r]);
            }
        }
}

// ---------------------------------------------------------------------------
// kqv: grid (65,12). BK=64 as two split 32-panels (32 MFMA / barrier pair).
//  x<64: KQV[m][n] = xb[m][:].wcat[n][:] + biascat[n], N=1536, ld 1536
//  x==64, y<4: vu2sel[r][c] = xb[selrow(r)][:].wcat[1536+c][:] + biascat[1536+c]
// ---------------------------------------------------------------------------
__global__ __launch_bounds__(256) void kqv_k(
    const u16* __restrict__ xb, const u16* __restrict__ wcat,
    const float* __restrict__ biascat, u16* __restrict__ KQV, u16* __restrict__ vu2sel)
{
    __shared__ u16 As[2][128 * 32];   // panel p: k = k0 + p*32
    __shared__ u16 Bs[2][128 * 32];
    const int tid  = threadIdx.x;
    const int wid  = tid >> 6;
    const int lane = tid & 63;
    const int l15  = lane & 15;
    const int quad = lane >> 4;
    const int wm = (wid & 1) * 64;
    const int wn = (wid >> 1) * 64;
    const int srow  = tid >> 2;
    const int skoff = (tid & 3) * 8;
    char* AsW = (char*)As + wid * 1024;   // wave-uniform base within panel 0 half 0
    char* BsW = (char*)Bs + wid * 1024;
    f32x4 acc[4][4] = {};

    const bool sel = (blockIdx.x == 64);
    if (sel && blockIdx.y >= 4) return;

    const u16 *Ag0, *Ag1, *Bg;
    const int bn = blockIdx.y * 128;
    if (!sel) {
        const int bm = blockIdx.x * 128;
        Ag0 = xb + (size_t)(bm + srow) * EMB_D + skoff;
        Ag1 = Ag0 + (size_t)64 * EMB_D;
        Bg  = wcat + (size_t)(bn + srow) * EMB_D + skoff;
    } else {
        const int r0 = srow, r1 = srow + 64;
        const int g0 = (r0 >> 5) * TDIM + (r0 & 31) * 64;
        const int g1 = (r1 >> 5) * TDIM + (r1 & 31) * 64;
        Ag0 = xb + (size_t)g0 * EMB_D + skoff;
        Ag1 = xb + (size_t)g1 * EMB_D + skoff;
        Bg  = wcat + (size_t)(1536 + bn + srow) * EMB_D + skoff;
    }

    for (int k0 = 0; k0 < EMB_D; k0 += 64) {
        __syncthreads();
        #pragma unroll
        for (int p = 0; p < 2; ++p) {
            const int kp = k0 + p * 32;
            __builtin_amdgcn_global_load_lds(
                (const __attribute__((address_space(1))) void*)(Ag0 + kp),
                (__attribute__((address_space(3))) void*)(AsW + p * 8192), 16, 0, 0);
            __builtin_amdgcn_global_load_lds(
                (const __attribute__((address_space(1))) void*)(Ag1 + kp),
                (__attribute__((address_space(3))) void*)(AsW + p * 8192 + 4096), 16, 0, 0);
            __builtin_amdgcn_global_load_lds(
                (const __attribute__((address_space(1))) void*)(Bg + kp),
                (__attribute__((address_space(3))) void*)(BsW + p * 8192), 16, 0, 0);
            __builtin_amdgcn_global_load_lds(
                (const __attribute__((address_space(1))) void*)(Bg + (size_t)64 * EMB_D + kp),
                (__attribute__((address_space(3))) void*)(BsW + p * 8192 + 4096), 16, 0, 0);
        }
        __syncthreads();

        #pragma unroll
        for (int p = 0; p < 2; ++p) {
            short8 a[4], b[4];
            #pragma unroll
            for (int i = 0; i < 4; ++i)
                a[i] = *(const short8*)((const short*)As[p] + (wm + 16*i + l15) * 32 + quad * 8);
            #pragma unroll
            for (int j = 0; j < 4; ++j)
                b[j] = *(const short8*)((const short*)Bs[p] + (wn + 16*j + l15) * 32 + quad * 8);
            #pragma unroll
            for (int i = 0; i < 4; ++i)
                #pragma unroll
                for (int j = 0; j < 4; ++j)
                    acc[i][j] = __builtin_amdgcn_mfma_f32_16x16x32_bf16(a[i], b[j], acc[i][j], 0, 0, 0);
        }
    }

    if (!sel) {
        const int bm = blockIdx.x * 128;
        #pragma unroll
        for (int i = 0; i < 4; ++i)
            #pragma unroll
            for (int j = 0; j < 4; ++j) {
                const int col = bn + wn + 16*j + l15;
                const float bvv = biascat[col];
                #pragma unroll
                for (int r = 0; r < 4; ++r) {
                    const int row = bm + wm + 16*i + quad*4 + r;
                    KQV[(size_t)row * LDK + col] = f2b(acc[i][j][r] + bvv);
                }
            }
    } else {
        #pragma unroll
        for (int i = 0; i < 4; ++i)
            #pragma unroll
            for (int j = 0; j < 4; ++j) {
                const int col = bn + wn + 16*j + l15;
                const float bvv = biascat[1536 + col];
                #pragma unroll
                for (int r = 0; r < 4; ++r) {
                    const int row = wm + 16*i + quad*4 + r;
                    vu2sel[(size_t)row * 512 + col] = f2b(acc[i][j][r] + bvv);
                }
            }
    }
}

// ---------------------------------------------------------------------------
// heads (R8, 256 threads): grid (32 blk, 4 b, 4 e-chunk).
//  Phase A (BK=64): S1 = K_blk.Q_blk^T (64x64), S2 = K_blk.Qsel^T (64x32),
//  K=512; masks c<=r / m<=blk; bf16 -> smA.
//  Phase B: out[:, e0:+128] = [S1|S2] @ [VU1_blk ; VU2sel]^T + bu (K=96).
// ---------------------------------------------------------------------------
__global__ __launch_bounds__(256) void heads_k(
    const u16* __restrict__ KQV, const u16* __restrict__ vu2sel,
    const float* __restrict__ bu, float* __restrict__ out)
{
    __shared__ u16 smA[64 * 104];     // [row][0:64 S1 | 64:96 S2]
    __shared__ u16 smVT[128 * 104];   // [e][0:64 VU1^T | 64:96 VU2sel^T]
    __shared__ u16 pK[2][64 * 32];    // BK=64 = 2 x 32 panels
    __shared__ u16 pQ[2][64 * 32];
    __shared__ u16 pQs[2][32 * 32];

    const int blk = blockIdx.x, b = blockIdx.y;
    const int e0 = blockIdx.z * 128;
    const int tid = threadIdx.x;
    const int wid = tid >> 6, lane = tid & 63;
    const int l15 = lane & 15, quad = lane >> 4;
    const size_t row0 = (size_t)b * TDIM + (size_t)blk * 64;
    const size_t brow = (size_t)b * TDIM;
    const int srow_base = 16 * wid + quad * 4;

    // ---- VU^T staging (independent of S; overlaps Phase A latency) ----
    #pragma unroll
    for (int it = 0; it < 4; ++it) {
        const int id = tid + 256 * it;
        const int c  = id & 63;
        const int eo = (id >> 6) * 8;
        short8 v = *(const short8*)(KQV + (row0 + c) * (size_t)LDK + 1024 + e0 + eo);
        #pragma unroll
        for (int i = 0; i < 8; ++i) smVT[(eo + i) * 104 + c] = (u16)v[i];
    }
    #pragma unroll
    for (int it = 0; it < 2; ++it) {
        const int id = tid + 256 * it;
        const int m  = id & 31;
        const int eo = (id >> 5) * 8;
        short8 v = *(const short8*)(vu2sel + ((size_t)(b * 32 + m)) * 512 + e0 + eo);
        #pragma unroll
        for (int i = 0; i < 8; ++i) smVT[(eo + i) * 104 + 64 + m] = (u16)v[i];
    }

    // ---- Phase A (BK=64, 8 iters) ----
    f32x4 s1[4] = {}; f32x4 s2[2] = {};
    const int srow  = tid >> 2;
    const int skoff = (tid & 3) * 8;
    const int qsrow = srow & 31;
    const int qsp   = tid >> 7;
    const u16* Kg  = KQV + (row0 + srow) * (size_t)LDK + skoff;
    const u16* Qg  = KQV + (row0 + srow) * (size_t)LDK + 512 + skoff;
    const u16* Qsg = KQV + (brow + (size_t)64 * qsrow) * (size_t)LDK + 512 + qsp * 32 + skoff;
    char* dK  = (char*)pK  + wid * 1024;
    char* dQ  = (char*)pQ  + wid * 1024;
    char* dQs = (char*)pQs + wid * 1024;

    for (int k0 = 0; k0 < 512; k0 += 64) {
        __syncthreads();
        __builtin_amdgcn_global_load_lds(
            (const __attribute__((address_space(1))) void*)(Kg + k0),
            (__attribute__((address_space(3))) void*)dK, 16, 0, 0);
        __builtin_amdgcn_global_load_lds(
            (const __attribute__((address_space(1))) void*)(Kg + k0 + 32),
            (__attribute__((address_space(3))) void*)(dK + 4096), 16, 0, 0);
        __builtin_amdgcn_global_load_lds(
            (const __attribute__((address_space(1))) void*)(Qg + k0),
            (__attribute__((address_space(3))) void*)dQ, 16, 0, 0);
        __builtin_amdgcn_global_load_lds(
            (const __attribute__((address_space(1))) void*)(Qg + k0 + 32),
            (__attribute__((address_space(3))) void*)(dQ + 4096), 16, 0, 0);
        __builtin_amdgcn_global_load_lds(
            (const __attribute__((address_space(1))) void*)(Qsg + k0),
            (__attribute__((address_space(3))) void*)dQs, 16, 0, 0);
        __syncthreads();

        short8 a0 = *(const short8*)(pK[0] + (16 * wid + l15) * 32 + quad * 8);
        short8 a1 = *(const short8*)(pK[1] + (16 * wid + l15) * 32 + quad * 8);
        #pragma unroll
        for (int j = 0; j < 4; ++j) {
            short8 b0 = *(const short8*)(pQ[0] + (16 * j + l15) * 32 + quad * 8);
            short8 b1 = *(const short8*)(pQ[1] + (16 * j + l15) * 32 + quad * 8);
            s1[j] = __builtin_amdgcn_mfma_f32_16x16x32_bf16(a0, b0, s1[j], 0, 0, 0);
            s1[j] = __builtin_amdgcn_mfma_f32_16x16x32_bf16(a1, b1, s1[j], 0, 0, 0);
        }
        #pragma unroll
        for (int j = 0; j < 2; ++j) {
            short8 b0 = *(const short8*)(pQs[0] + (16 * j + l15) * 32 + quad * 8);
            short8 b1 = *(const short8*)(pQs[1] + (16 * j + l15) * 32 + quad * 8);
            s2[j] = __builtin_amdgcn_mfma_f32_16x16x32_bf16(a0, b0, s2[j], 0, 0, 0);
            s2[j] = __builtin_amdgcn_mfma_f32_16x16x32_bf16(a1, b1, s2[j], 0, 0, 0);
        }
    }

    #pragma unroll
    for (int j = 0; j < 4; ++j)
        #pragma unroll
        for (int r = 0; r < 4; ++r) {
            const int rr = srow_base + r;
            const int cc = 16 * j + l15;
            smA[rr * 104 + cc] = f2b((cc <= rr) ? s1[j][r] : 0.0f);
        }
    #pragma unroll
    for (int j = 0; j < 2; ++j)
        #pragma unroll
        for (int r = 0; r < 4; ++r) {
            const int m  = 16 * j + l15;
            const int rr = srow_base + r;
            smA[rr * 104 + 64 + m] = f2b((m <= blk) ? s2[j][r] : 0.0f);
        }
    __syncthreads();

    // ---- Phase B: out = [S1|S2] @ smVT^T  (K=96, N=128) ----
    f32x4 o[8] = {};
    const u16* arow = smA + (16 * wid + l15) * 104;
    #pragma unroll
    for (int ks = 0; ks < 3; ++ks) {
        short8 as = *(const short8*)(arow + 32 * ks + quad * 8);
        #pragma unroll
        for (int nt = 0; nt < 8; ++nt) {
            short8 bs = *(const short8*)(smVT + (16 * nt + l15) * 104 + 32 * ks + quad * 8);
            o[nt] = __builtin_amdgcn_mfma_f32_16x16x32_bf16(as, bs, o[nt], 0, 0, 0);
        }
    }
    #pragma unroll
    for (int nt = 0; nt < 8; ++nt) {
        const int col = e0 + 16 * nt + l15;
        const float bvv = bu[col];
        #pragma unroll
        for (int r = 0; r < 4; ++r)
            out[(row0 + srow_base + r) * (size_t)EMB_D + col] = o[nt][r] + bvv;
    }
}

extern "C" void kernel_launch(void* const* d_in, const int* in_sizes, int n_in,
                              void* d_out, int out_size, void* d_ws, size_t ws_size,
                              hipStream_t stream)
{
    const float* x  = (const float*)d_in[0];
    const float* Wk = (const float*)d_in[1];
    const float* bk = (const float*)d_in[2];
    const float* Wq = (const float*)d_in[3];
    const float* bq = (const float*)d_in[4];
    const float* Wv = (const float*)d_in[5];
    const float* bv = (const float*)d_in[6];
    const float* Wu = (const float*)d_in[7];
    const float* bu = (const float*)d_in[8];
    float* out = (float*)d_out;

    char* w = (char*)d_ws;
    u16*   KQV     = (u16*)  (w + ((size_t)0  << 20));
    u16*   xb      = (u16*)  (w + ((size_t)24 << 20));
    u16*   wcat    = (u16*)  (w + ((size_t)32 << 20));
    u16*   vu2sel  = (u16*)  (w + ((size_t)34 << 20));
    u16*   wvtb    = (u16*)  (w + ((size_t)35 << 20));
    u16*   wub     = (u16*)  (w + ((size_t)36 << 20));
    float* biascat = (float*)(w + ((size_t)37 << 20));

    dim3 blk(256);
    hipLaunchKernelGGL(prep_k, dim3(5201), blk, 0, stream,
                       x, Wk, Wq, Wv, Wu, bk, bq, bv, xb, wcat, wvtb, wub, biascat);
    hipLaunchKernelGGL(wc_gemm_k, dim3(8, 4), blk, 0, stream, wub, wvtb, wcat);
    hipLaunchKernelGGL(kqv_k, dim3(65, 12), blk, 0, stream,
                       xb, wcat, biascat, KQV, vu2sel);
    hipLaunchKernelGGL(heads_k, dim3(NBLK, BB, 4), blk, 0, stream,
                       KQV, vu2sel, bu, out);
}